// Round 11
// baseline (8224.884 us; speedup 1.0000x reference)
//
#include <hip/hip_runtime.h>

// Problem constants: B=64, T=512, IN=256, H=1024, L=2, OUT=128
#define B_ 64
#define T_ 512
#define IN_ 256
#define H_ 1024
#define OUT_ 128
#define NBLK 64
#define NTHR 512

typedef __attribute__((ext_vector_type(4))) float f32x4;
typedef __attribute__((ext_vector_type(8))) short s16x8;
typedef __attribute__((ext_vector_type(4))) short s16x4;
typedef unsigned short u16;

#define MFMA16 __builtin_amdgcn_mfma_f32_16x16x32_bf16

union FragU { s16x8 v; unsigned d[4]; };
union Frag4U { s16x4 v; unsigned d[2]; };

// fp32 -> bf16 RNE
__device__ __forceinline__ u16 f2bf(float f) {
  union { float f; unsigned u; } v; v.f = f;
  unsigned r = v.u + 0x7fffu + ((v.u >> 16) & 1u);
  return (u16)(r >> 16);
}
__device__ __forceinline__ float bf2f(u16 h) {
  union { unsigned u; float f; } v; v.u = ((unsigned)h) << 16;
  return v.f;
}
__device__ __forceinline__ s16x8 cvt8(const float* __restrict__ p) {
  float4 a = *(const float4*)p;
  float4 b = *(const float4*)(p + 4);
  s16x8 r;
  r[0] = (short)f2bf(a.x); r[1] = (short)f2bf(a.y);
  r[2] = (short)f2bf(a.z); r[3] = (short)f2bf(a.w);
  r[4] = (short)f2bf(b.x); r[5] = (short)f2bf(b.y);
  r[6] = (short)f2bf(b.z); r[7] = (short)f2bf(b.w);
  return r;
}

// tanh via hardware exp. Output in [-1,1] -> bf16 bit14 always 0; poison
// 0xFFFF has bit14 set. Data-poll readiness detector (R9-proven).
__device__ __forceinline__ float fast_tanh(float x) {
  float e = __expf(2.0f * x);
  return 1.0f - 2.0f * __builtin_amdgcn_rcpf(e + 1.0f);
}

// Write-through 2B store to MALL (validated rounds 4-9).
__device__ __forceinline__ void store_wt_u16(u16* p, u16 v) {
  unsigned d = v;
  asm volatile("global_store_short %0, %1, off sc0 sc1" :: "v"(p), "v"(d) : "memory");
}

// ---------------------------------------------------------------------------
// prologue kernels (validated rounds 3-9, unchanged)
// ---------------------------------------------------------------------------
__global__ __launch_bounds__(256) void cvt_x(const float* __restrict__ x,
                                             u16* __restrict__ xbf) {
  int i4 = blockIdx.x * 256 + threadIdx.x;
  int r = i4 >> 6;
  int kc = (i4 & 63) * 4;
  int t = r >> 6, b = r & 63;
  float4 v = *(const float4*)(x + ((size_t)b * T_ + t) * IN_ + kc);
  s16x4 o;
  o[0] = (short)f2bf(v.x); o[1] = (short)f2bf(v.y);
  o[2] = (short)f2bf(v.z); o[3] = (short)f2bf(v.w);
  *(s16x4*)(xbf + (size_t)r * IN_ + kc) = o;
}

__global__ __launch_bounds__(256) void cvt_w(const float* __restrict__ w,
                                             u16* __restrict__ wbf) {
  int i = blockIdx.x * 256 + threadIdx.x;
  float4 v = *(const float4*)(w + (size_t)i * 4);
  s16x4 o;
  o[0] = (short)f2bf(v.x); o[1] = (short)f2bf(v.y);
  o[2] = (short)f2bf(v.z); o[3] = (short)f2bf(v.w);
  *(s16x4*)(wbf + (size_t)i * 4) = o;
}

__global__ __launch_bounds__(256) void xw0_mfma(const u16* __restrict__ xbf,
                                                const u16* __restrict__ w0bf,
                                                const float* __restrict__ bih,
                                                const float* __restrict__ bhh,
                                                u16* __restrict__ xw0) {
  __shared__ char ldsW[64 * 512];
  const int tid = threadIdx.x;
  const int j0 = blockIdx.x * 64;
  const int r0 = blockIdx.y * 64;

  for (int c = tid; c < 64 * 32; c += 256) {
    int r = c >> 5, kc = c & 31;
    s16x8 w = *(const s16x8*)(w0bf + (size_t)(j0 + r) * IN_ + kc * 8);
    *(s16x8*)(ldsW + r * 512 + ((kc * 16) ^ ((r & 7) << 4))) = w;
  }
  __syncthreads();

  const int wv = tid >> 6, lane = tid & 63;
  const int col = lane & 15, kg = lane >> 4;
  const int rr = r0 + wv * 16 + col;
  const u16* aRow = xbf + (size_t)rr * IN_ + kg * 8;

  f32x4 acc[4] = {};
#pragma unroll
  for (int k0 = 0; k0 < IN_; k0 += 32) {
    s16x8 a = *(const s16x8*)(aRow + k0);
#pragma unroll
    for (int n = 0; n < 4; ++n) {
      int jr = n * 16 + col;
      s16x8 b = *(const s16x8*)(ldsW + jr * 512 + ((((k0 + kg * 8) << 1)) ^ ((jr & 7) << 4)));
      acc[n] = MFMA16(a, b, acc[n], 0, 0, 0);
    }
  }
#pragma unroll
  for (int n = 0; n < 4; ++n) {
    int j = j0 + n * 16 + col;
    float bs = bih[j] + bhh[j];
#pragma unroll
    for (int q = 0; q < 4; ++q) {
      int r = r0 + wv * 16 + kg * 4 + q;
      xw0[(size_t)r * H_ + j] = f2bf(acc[n][q] + bs);
    }
  }
}

// ---------------------------------------------------------------------------
// Self-timed persistent kernel in the R9-PROVEN launch shape:
// 64 blocks x 512 threads, 96KB dyn LDS. Block jg owns 16 j-cols.
// Waves 0-3 = layer 0 (b-tile wv*16):   poll ys[s-1] -> 32 MFMA -> store ys[s]
// Waves 4-7 = layer 1 (b-tile (wv-4)*16): poll ys[t] -> 32 MFMA (Wih1),
//   then poll h1[t-1] (same af regs) -> 32 MFMA (Whh1) -> store h1[t].
// ZERO barriers / flags in the loops. ys: TxBxH poisoned 0xFF per launch;
// h1: depth-8 rotation, producer pre-poisons slot (t+4)&7 before its
// poll-drain (vmcnt(0)) -> poison provably visible before that slot's data.
// Finale: block jg builds out row jg from data-polled ys[511] / h1 slot 7.
// VGPR discipline: ONE af[32] array, offset:-immediate loads (1 base addr).
// ---------------------------------------------------------------------------
__global__ __launch_bounds__(NTHR, 1) void rnn_seq(
    const float* __restrict__ Whh0, const float* __restrict__ Wih1,
    const float* __restrict__ Whh1, const float* __restrict__ bih1,
    const float* __restrict__ bhh1, const float* __restrict__ Wlin,
    const float* __restrict__ blin, const u16* __restrict__ xw0bf,
    u16* __restrict__ ys0, u16* __restrict__ h1rot, float* __restrict__ out) {
  extern __shared__ char lds[];
  char* ldsW0 = lds;           // 16 x 2048 B (32 KB)
  char* ldsW1 = lds + 32768;   // 16 x 4096 B (64 KB)

  const int tid = threadIdx.x;
  const int jg = blockIdx.x;   // 0..63
  const int j0 = jg * 16;
  const int wv = tid >> 6, lane = tid & 63;
  const int col = lane & 15, kg = lane >> 4;
  const int sw = (col & 7) << 4;
  const int bt = wv & 3;
  const int b0 = bt * 16;
  const bool isL1 = wv >= 4;
  const int jt = j0 + col;

  // stage W0 slice (16 x 1024 bf16), swizzled (all 8 waves help)
  for (int c = tid; c < 16 * 128; c += NTHR) {
    int r = c >> 7, kc = c & 127;
    s16x8 w = cvt8(Whh0 + (size_t)(j0 + r) * H_ + kc * 8);
    *(s16x8*)(ldsW0 + r * 2048 + ((kc * 16) ^ ((r & 7) << 4))) = w;
  }
  // stage W1 slice (16 x 2048 bf16): [0,1024)=Wih1, [1024,2048)=Whh1
  for (int c = tid; c < 16 * 256; c += NTHR) {
    int r = c >> 8, kc = c & 255;
    const float* src = (kc < 128) ? (Wih1 + (size_t)(j0 + r) * H_ + kc * 8)
                                  : (Whh1 + (size_t)(j0 + r) * H_ + (kc - 128) * 8);
    *(s16x8*)(ldsW1 + r * 4096 + ((kc * 16) ^ ((r & 7) << 4))) = cvt8(src);
  }
  __syncthreads();

  if (!isL1) {
    // ===================== layer-0 waves =====================
    const char* w0B = ldsW0 + col * 2048;
    for (int s = 0; s < T_; ++s) {
      const u16* xwp = xw0bf + ((size_t)s * B_ + b0 + kg * 4) * H_ + jt;
      u16 xv0 = xwp[0], xv1 = xwp[H_], xv2 = xwp[2 * H_], xv3 = xwp[3 * H_];
      f32x4 acc0 = {}, acc1 = {};
      if (s > 0) {
        const u16* aRow = ys0 + ((size_t)(s - 1) * B_ + b0 + col) * H_ + kg * 8;
        FragU af[32];
        unsigned poi;
        do {  // DATA-POLL: the poll IS the operand load
#pragma unroll
          for (int i = 0; i < 32; ++i)
            asm volatile("global_load_dwordx4 %0, %1, off offset:%c2 sc0 sc1"
                         : "=v"(af[i].v) : "v"(aRow), "n"(i * 64) : "memory");
          asm volatile("s_waitcnt vmcnt(0)" ::: "memory");
          __builtin_amdgcn_sched_barrier(0);
          poi = 0u;
#pragma unroll
          for (int i = 0; i < 32; ++i)
            poi |= af[i].d[0] | af[i].d[1] | af[i].d[2] | af[i].d[3];
        } while (__ballot((poi & 0x40004000u) != 0u) != 0ull);
        __builtin_amdgcn_sched_barrier(0);
#pragma unroll
        for (int i = 0; i < 32; i += 2) {
          const int kb0 = ((i * 32 + kg * 8) << 1);
          const int kb1 = (((i + 1) * 32 + kg * 8) << 1);
          acc0 = MFMA16(af[i].v, *(const s16x8*)(w0B + (kb0 ^ sw)), acc0, 0, 0, 0);
          acc1 = MFMA16(af[i + 1].v, *(const s16x8*)(w0B + (kb1 ^ sw)), acc1, 0, 0, 0);
        }
      }
      f32x4 aY = acc0 + acc1;
      u16* ysC = ys0 + ((size_t)s * B_ + b0 + kg * 4) * H_ + jt;
      store_wt_u16(ysC + 0 * H_, f2bf(fast_tanh(aY[0] + bf2f(xv0))));
      store_wt_u16(ysC + 1 * H_, f2bf(fast_tanh(aY[1] + bf2f(xv1))));
      store_wt_u16(ysC + 2 * H_, f2bf(fast_tanh(aY[2] + bf2f(xv2))));
      store_wt_u16(ysC + 3 * H_, f2bf(fast_tanh(aY[3] + bf2f(xv3))));
      // no drain, no flag: consumers poll the data words themselves
    }
  } else {
    // ===================== layer-1 waves =====================
    const char* w1B = ldsW1 + col * 4096;
    const float bias1 = bih1[jt] + bhh1[jt];
    for (int t = 0; t < T_; ++t) {
      {  // pre-poison slot (t+4)&7 (own output cells); drained by next vmcnt(0)
        u16* pz = h1rot + ((size_t)((t + 4) & 7)) * (B_ * H_) +
                  (size_t)(b0 + kg * 4) * H_ + jt;
        store_wt_u16(pz + 0 * H_, 0xFFFFu);
        store_wt_u16(pz + 1 * H_, 0xFFFFu);
        store_wt_u16(pz + 2 * H_, 0xFFFFu);
        store_wt_u16(pz + 3 * H_, 0xFFFFu);
      }
      f32x4 acc0 = {}, acc1 = {};
      {  // poll ys[t], consume with Wih1 half (af dead after)
        const u16* aRow = ys0 + ((size_t)t * B_ + b0 + col) * H_ + kg * 8;
        FragU af[32];
        unsigned poi;
        do {
#pragma unroll
          for (int i = 0; i < 32; ++i)
            asm volatile("global_load_dwordx4 %0, %1, off offset:%c2 sc0 sc1"
                         : "=v"(af[i].v) : "v"(aRow), "n"(i * 64) : "memory");
          asm volatile("s_waitcnt vmcnt(0)" ::: "memory");
          __builtin_amdgcn_sched_barrier(0);
          poi = 0u;
#pragma unroll
          for (int i = 0; i < 32; ++i)
            poi |= af[i].d[0] | af[i].d[1] | af[i].d[2] | af[i].d[3];
        } while (__ballot((poi & 0x40004000u) != 0u) != 0ull);
        __builtin_amdgcn_sched_barrier(0);
#pragma unroll
        for (int i = 0; i < 32; i += 2) {
          const int kb0 = ((i * 32 + kg * 8) << 1);
          const int kb1 = (((i + 1) * 32 + kg * 8) << 1);
          acc0 = MFMA16(af[i].v, *(const s16x8*)(w1B + (kb0 ^ sw)), acc0, 0, 0, 0);
          acc1 = MFMA16(af[i + 1].v, *(const s16x8*)(w1B + (kb1 ^ sw)), acc1, 0, 0, 0);
        }
      }
      if (t > 0) {  // poll h1[t-1], consume with Whh1 half (af regs reused)
        const u16* hRow = h1rot + ((size_t)((t - 1) & 7)) * (B_ * H_) +
                          (size_t)(b0 + col) * H_ + kg * 8;
        FragU af[32];
        unsigned poi;
        do {
#pragma unroll
          for (int i = 0; i < 32; ++i)
            asm volatile("global_load_dwordx4 %0, %1, off offset:%c2 sc0 sc1"
                         : "=v"(af[i].v) : "v"(hRow), "n"(i * 64) : "memory");
          asm volatile("s_waitcnt vmcnt(0)" ::: "memory");
          __builtin_amdgcn_sched_barrier(0);
          poi = 0u;
#pragma unroll
          for (int i = 0; i < 32; ++i)
            poi |= af[i].d[0] | af[i].d[1] | af[i].d[2] | af[i].d[3];
        } while (__ballot((poi & 0x40004000u) != 0u) != 0ull);
        __builtin_amdgcn_sched_barrier(0);
#pragma unroll
        for (int i = 0; i < 32; i += 2) {
          const int kb0 = 2048 + ((i * 32 + kg * 8) << 1);
          const int kb1 = 2048 + (((i + 1) * 32 + kg * 8) << 1);
          acc0 = MFMA16(af[i].v, *(const s16x8*)(w1B + (kb0 ^ sw)), acc0, 0, 0, 0);
          acc1 = MFMA16(af[i + 1].v, *(const s16x8*)(w1B + (kb1 ^ sw)), acc1, 0, 0, 0);
        }
      }
      f32x4 aH = acc0 + acc1;
      u16* hc = h1rot + ((size_t)(t & 7)) * (B_ * H_) +
                (size_t)(b0 + kg * 4) * H_ + jt;
      store_wt_u16(hc + 0 * H_, f2bf(fast_tanh(aH[0] + bias1)));
      store_wt_u16(hc + 1 * H_, f2bf(fast_tanh(aH[1] + bias1)));
      store_wt_u16(hc + 2 * H_, f2bf(fast_tanh(aH[2] + bias1)));
      store_wt_u16(hc + 3 * H_, f2bf(fast_tanh(aH[3] + bias1)));
    }
  }

  __syncthreads();  // uniform: both wave groups finished their loops

  // ===================== finale: out row b = jg =====================
  u16* rowbuf = (u16*)lds;  // reuse W0 region (dead now)
  {
    Frag4U q;
    if (tid < 256) {  // ys[511] row jg, data-poll (4 u16 per thread)
      const u16* p = ys0 + ((size_t)(T_ - 1) * B_ + jg) * H_ + tid * 4;
      do {
        asm volatile("global_load_dwordx2 %0, %1, off sc0 sc1\n\ts_waitcnt vmcnt(0)"
                     : "=v"(q.v) : "v"(p) : "memory");
      } while (__ballot(((q.d[0] | q.d[1]) & 0x40004000u) != 0u) != 0ull);
      *(s16x4*)(rowbuf + tid * 4) = q.v;
    } else {  // h1[511] = slot 7, row jg, data-poll
      const u16* p = h1rot + (size_t)7 * (B_ * H_) + (size_t)jg * H_ + (tid - 256) * 4;
      do {
        asm volatile("global_load_dwordx2 %0, %1, off sc0 sc1\n\ts_waitcnt vmcnt(0)"
                     : "=v"(q.v) : "v"(p) : "memory");
      } while (__ballot(((q.d[0] | q.d[1]) & 0x40004000u) != 0u) != 0ull);
      *(s16x4*)(rowbuf + 1024 + (tid - 256) * 4) = q.v;
    }
  }
  asm volatile("s_waitcnt lgkmcnt(0)" ::: "memory");
  __syncthreads();

  if (tid < OUT_) {
    const int o = tid;
    const float* wr = Wlin + (size_t)o * (2 * H_);
    float acc = blin[o];
#pragma unroll 4
    for (int k = 0; k < 2 * H_; k += 8) {
      s16x8 h = *(const s16x8*)(rowbuf + k);
      float4 w0 = *(const float4*)(wr + k);
      float4 w1 = *(const float4*)(wr + k + 4);
      acc += bf2f((u16)h[0]) * w0.x + bf2f((u16)h[1]) * w0.y +
             bf2f((u16)h[2]) * w0.z + bf2f((u16)h[3]) * w0.w +
             bf2f((u16)h[4]) * w1.x + bf2f((u16)h[5]) * w1.y +
             bf2f((u16)h[6]) * w1.z + bf2f((u16)h[7]) * w1.w;
    }
    out[jg * OUT_ + o] = 1.0f / (1.0f + expf(-acc));
  }
}

// ---------------------------------------------------------------------------
extern "C" void kernel_launch(void* const* d_in, const int* in_sizes, int n_in,
                              void* d_out, int out_size, void* d_ws, size_t ws_size,
                              hipStream_t stream) {
  const float* x    = (const float*)d_in[0];
  const float* Wih0 = (const float*)d_in[1];
  const float* Whh0 = (const float*)d_in[2];
  const float* bih0 = (const float*)d_in[3];
  const float* bhh0 = (const float*)d_in[4];
  const float* Wih1 = (const float*)d_in[5];
  const float* Whh1 = (const float*)d_in[6];
  const float* bih1 = (const float*)d_in[7];
  const float* bhh1 = (const float*)d_in[8];
  const float* Wlin = (const float*)d_in[9];
  const float* blin = (const float*)d_in[10];
  float* out = (float*)d_out;

  char* ws = (char*)d_ws;
  const size_t TBH = (size_t)T_ * B_ * H_;
  u16* xw0bf = (u16*)ws;                     // 64 MiB
  u16* ys0   = (u16*)(ws + (64ull << 20));   // 64 MiB (poisoned per launch)
  u16* xbf   = ys0;                          // prologue-only aliases
  u16* w0bf  = ys0 + (size_t)T_ * B_ * IN_;  //  (dead before poisoning)
  u16* h1rot = (u16*)(ws + (128ull << 20));  // 8 x 128 KiB rotation (poisoned)

  cvt_x<<<8192, 256, 0, stream>>>(x, xbf);
  cvt_w<<<256, 256, 0, stream>>>(Wih0, w0bf);
  xw0_mfma<<<dim3(16, 512), 256, 0, stream>>>(xbf, w0bf, bih0, bhh0, xw0bf);

  // poison AFTER xw0_mfma consumed the aliased xbf/w0bf (stream-ordered)
  hipMemsetAsync(ys0, 0xFF, TBH * 2, stream);
  hipMemsetAsync(h1rot, 0xFF, (size_t)8 * B_ * H_ * 2, stream);

  const int dyn_lds = 98304;  // 32K W0 + 64K W1 (R3-proven size class)
  hipFuncSetAttribute((const void*)rnn_seq, hipFuncAttributeMaxDynamicSharedMemorySize,
                      dyn_lds);
  void* args[] = {&Whh0, &Wih1, &Whh1, &bih1, &bhh1, &Wlin,
                  &blin, &xw0bf, &ys0, &h1rot, &out};
  hipLaunchCooperativeKernel((const void*)rnn_seq, dim3(NBLK), dim3(NTHR), args, dyn_lds,
                             stream);
}

// Round 12
// 6950.168 us; speedup vs baseline: 1.1834x; 1.1834x over previous
//
#include <hip/hip_runtime.h>

// Problem constants: B=64, T=512, IN=256, H=1024, L=2, OUT=128
#define B_ 64
#define T_ 512
#define IN_ 256
#define H_ 1024
#define OUT_ 128
#define NBLK 64
#define NTHR 512

typedef __attribute__((ext_vector_type(4))) float f32x4;
typedef __attribute__((ext_vector_type(8))) short s16x8;
typedef __attribute__((ext_vector_type(4))) short s16x4;
typedef unsigned short u16;

#define MFMA16 __builtin_amdgcn_mfma_f32_16x16x32_bf16

union FragU { s16x8 v; unsigned d[4]; };

// fp32 -> bf16 RNE
__device__ __forceinline__ u16 f2bf(float f) {
  union { float f; unsigned u; } v; v.f = f;
  unsigned r = v.u + 0x7fffu + ((v.u >> 16) & 1u);
  return (u16)(r >> 16);
}
__device__ __forceinline__ float bf2f(u16 h) {
  union { unsigned u; float f; } v; v.u = ((unsigned)h) << 16;
  return v.f;
}
__device__ __forceinline__ s16x8 cvt8(const float* __restrict__ p) {
  float4 a = *(const float4*)p;
  float4 b = *(const float4*)(p + 4);
  s16x8 r;
  r[0] = (short)f2bf(a.x); r[1] = (short)f2bf(a.y);
  r[2] = (short)f2bf(a.z); r[3] = (short)f2bf(a.w);
  r[4] = (short)f2bf(b.x); r[5] = (short)f2bf(b.y);
  r[6] = (short)f2bf(b.z); r[7] = (short)f2bf(b.w);
  return r;
}

// tanh via hardware exp (validated rounds 5-11).
__device__ __forceinline__ float fast_tanh(float x) {
  float e = __expf(2.0f * x);
  return 1.0f - 2.0f * __builtin_amdgcn_rcpf(e + 1.0f);
}

// Write-through 2B store to MALL (validated rounds 4-11).
__device__ __forceinline__ void store_wt_u16(u16* p, u16 v) {
  unsigned d = v;
  asm volatile("global_store_short %0, %1, off sc0 sc1" :: "v"(p), "v"(d) : "memory");
}

// Cheap flag poll: 64 flags (one per producer block), 4B per lane per retry.
// Flags are FRESH addresses per step (zeroed each launch) -> nonzero == done.
__device__ __forceinline__ void poll_flags(const unsigned* fp, int lane) {
  unsigned fv;
  do {
    asm volatile("global_load_dword %0, %1, off sc0 sc1\n\ts_waitcnt vmcnt(0)"
                 : "=v"(fv) : "v"(fp + lane) : "memory");
  } while (__ballot(fv == 0u) != 0ull);
  __builtin_amdgcn_sched_barrier(0);
}

// ---------------------------------------------------------------------------
// prologue kernels (validated rounds 3-11, unchanged)
// ---------------------------------------------------------------------------
__global__ __launch_bounds__(256) void cvt_x(const float* __restrict__ x,
                                             u16* __restrict__ xbf) {
  int i4 = blockIdx.x * 256 + threadIdx.x;
  int r = i4 >> 6;
  int kc = (i4 & 63) * 4;
  int t = r >> 6, b = r & 63;
  float4 v = *(const float4*)(x + ((size_t)b * T_ + t) * IN_ + kc);
  s16x4 o;
  o[0] = (short)f2bf(v.x); o[1] = (short)f2bf(v.y);
  o[2] = (short)f2bf(v.z); o[3] = (short)f2bf(v.w);
  *(s16x4*)(xbf + (size_t)r * IN_ + kc) = o;
}

__global__ __launch_bounds__(256) void cvt_w(const float* __restrict__ w,
                                             u16* __restrict__ wbf) {
  int i = blockIdx.x * 256 + threadIdx.x;
  float4 v = *(const float4*)(w + (size_t)i * 4);
  s16x4 o;
  o[0] = (short)f2bf(v.x); o[1] = (short)f2bf(v.y);
  o[2] = (short)f2bf(v.z); o[3] = (short)f2bf(v.w);
  *(s16x4*)(wbf + (size_t)i * 4) = o;
}

__global__ __launch_bounds__(256) void xw0_mfma(const u16* __restrict__ xbf,
                                                const u16* __restrict__ w0bf,
                                                const float* __restrict__ bih,
                                                const float* __restrict__ bhh,
                                                u16* __restrict__ xw0) {
  __shared__ char ldsW[64 * 512];
  const int tid = threadIdx.x;
  const int j0 = blockIdx.x * 64;
  const int r0 = blockIdx.y * 64;

  for (int c = tid; c < 64 * 32; c += 256) {
    int r = c >> 5, kc = c & 31;
    s16x8 w = *(const s16x8*)(w0bf + (size_t)(j0 + r) * IN_ + kc * 8);
    *(s16x8*)(ldsW + r * 512 + ((kc * 16) ^ ((r & 7) << 4))) = w;
  }
  __syncthreads();

  const int wv = tid >> 6, lane = tid & 63;
  const int col = lane & 15, kg = lane >> 4;
  const int rr = r0 + wv * 16 + col;
  const u16* aRow = xbf + (size_t)rr * IN_ + kg * 8;

  f32x4 acc[4] = {};
#pragma unroll
  for (int k0 = 0; k0 < IN_; k0 += 32) {
    s16x8 a = *(const s16x8*)(aRow + k0);
#pragma unroll
    for (int n = 0; n < 4; ++n) {
      int jr = n * 16 + col;
      s16x8 b = *(const s16x8*)(ldsW + jr * 512 + ((((k0 + kg * 8) << 1)) ^ ((jr & 7) << 4)));
      acc[n] = MFMA16(a, b, acc[n], 0, 0, 0);
    }
  }
#pragma unroll
  for (int n = 0; n < 4; ++n) {
    int j = j0 + n * 16 + col;
    float bs = bih[j] + bhh[j];
#pragma unroll
    for (int q = 0; q < 4; ++q) {
      int r = r0 + wv * 16 + kg * 4 + q;
      xw0[(size_t)r * H_ + j] = f2bf(acc[n][q] + bs);
    }
  }
}

// ---------------------------------------------------------------------------
// Self-timed persistent kernel, FLAG-GATED protocol (cheap polls, single
// operand load, plain cached ys loads). 64 blocks x 512 thr (R9/R11-proven
// shape). Block jg owns 16 j-cols; waves 0-3 = L0 (b-tile wv), waves 4-7 =
// L1 (b-tile wv-4). NO barriers/grid sync in loops.
//   producer: WT data stores -> vmcnt(0) -> flag store (R9-proven ordering)
//   consumer: poll 64 flags (4B/lane/retry) -> load operands ONCE
// ys loads are PLAIN (L2-cached): ys addresses are write-once per dispatch
// and only ever touched after their flag is set -> first touch fetches fresh
// from MALL, then L2 serves the 63 other readers. h1 loads stay sc0 sc1
// (rotation slots reuse addresses; flag-lockstep bounds skew so depth 8 is
// overwrite-safe, but L2 could hold week-old copies -> bypass).
// ---------------------------------------------------------------------------
__global__ __launch_bounds__(NTHR, 1) void rnn_seq(
    const float* __restrict__ Whh0, const float* __restrict__ Wih1,
    const float* __restrict__ Whh1, const float* __restrict__ bih1,
    const float* __restrict__ bhh1, const float* __restrict__ Wlin,
    const float* __restrict__ blin, const u16* __restrict__ xw0bf,
    u16* __restrict__ ys0, u16* __restrict__ h1rot,
    unsigned* __restrict__ ysd, unsigned* __restrict__ h1d,
    float* __restrict__ out) {
  extern __shared__ char lds[];
  char* ldsW0 = lds;           // 16 x 2048 B (32 KB)
  char* ldsW1 = lds + 32768;   // 16 x 4096 B (64 KB)

  const int tid = threadIdx.x;
  const int jg = blockIdx.x;   // 0..63
  const int j0 = jg * 16;
  const int wv = tid >> 6, lane = tid & 63;
  const int col = lane & 15, kg = lane >> 4;
  const int sw = (col & 7) << 4;
  const int bt = wv & 3;
  const int b0 = bt * 16;
  const bool isL1 = wv >= 4;
  const int jt = j0 + col;

  // stage W0 slice (16 x 1024 bf16), swizzled (all 8 waves help)
  for (int c = tid; c < 16 * 128; c += NTHR) {
    int r = c >> 7, kc = c & 127;
    s16x8 w = cvt8(Whh0 + (size_t)(j0 + r) * H_ + kc * 8);
    *(s16x8*)(ldsW0 + r * 2048 + ((kc * 16) ^ ((r & 7) << 4))) = w;
  }
  // stage W1 slice (16 x 2048 bf16): [0,1024)=Wih1, [1024,2048)=Whh1
  for (int c = tid; c < 16 * 256; c += NTHR) {
    int r = c >> 8, kc = c & 255;
    const float* src = (kc < 128) ? (Wih1 + (size_t)(j0 + r) * H_ + kc * 8)
                                  : (Whh1 + (size_t)(j0 + r) * H_ + (kc - 128) * 8);
    *(s16x8*)(ldsW1 + r * 4096 + ((kc * 16) ^ ((r & 7) << 4))) = cvt8(src);
  }
  __syncthreads();

  if (!isL1) {
    // ===================== layer-0 waves =====================
    const char* w0B = ldsW0 + col * 2048;
    for (int s = 0; s < T_; ++s) {
      const u16* xwp = xw0bf + ((size_t)s * B_ + b0 + kg * 4) * H_ + jt;
      u16 xv0 = xwp[0], xv1 = xwp[H_], xv2 = xwp[2 * H_], xv3 = xwp[3 * H_];
      f32x4 acc0 = {}, acc1 = {};
      if (s > 0) {
        poll_flags(ysd + ((size_t)(s - 1) * 4 + bt) * 64, lane);
        // operand slab: plain (L2-cached) loads — safe post-flag (write-once)
        const u16* aRow = ys0 + ((size_t)(s - 1) * B_ + b0 + col) * H_ + kg * 8;
        FragU af[32];
#pragma unroll
        for (int i = 0; i < 32; ++i) af[i].v = *(const s16x8*)(aRow + i * 32);
#pragma unroll
        for (int i = 0; i < 32; i += 2) {
          const int kb0 = ((i * 32 + kg * 8) << 1);
          const int kb1 = (((i + 1) * 32 + kg * 8) << 1);
          acc0 = MFMA16(af[i].v, *(const s16x8*)(w0B + (kb0 ^ sw)), acc0, 0, 0, 0);
          acc1 = MFMA16(af[i + 1].v, *(const s16x8*)(w0B + (kb1 ^ sw)), acc1, 0, 0, 0);
        }
      }
      f32x4 aY = acc0 + acc1;
      u16* ysC = ys0 + ((size_t)s * B_ + b0 + kg * 4) * H_ + jt;
      store_wt_u16(ysC + 0 * H_, f2bf(fast_tanh(aY[0] + bf2f(xv0))));
      store_wt_u16(ysC + 1 * H_, f2bf(fast_tanh(aY[1] + bf2f(xv1))));
      store_wt_u16(ysC + 2 * H_, f2bf(fast_tanh(aY[2] + bf2f(xv2))));
      store_wt_u16(ysC + 3 * H_, f2bf(fast_tanh(aY[3] + bf2f(xv3))));
      asm volatile("s_waitcnt vmcnt(0)" ::: "memory");  // data at MALL...
      if (lane == 0) {                                   // ...then flag
        unsigned one = 1u;
        asm volatile("global_store_dword %0, %1, off sc0 sc1"
                     :: "v"(ysd + ((size_t)s * 4 + bt) * 64 + jg), "v"(one)
                     : "memory");
      }
    }
  } else {
    // ===================== layer-1 waves =====================
    const char* w1B = ldsW1 + col * 4096;
    const float bias1 = bih1[jt] + bhh1[jt];
    for (int t = 0; t < T_; ++t) {
      f32x4 acc0 = {}, acc1 = {};
      FragU af[32];
      {  // ys[t] term: flag poll -> plain cached slab load -> Wih1 MFMAs
        poll_flags(ysd + ((size_t)t * 4 + bt) * 64, lane);
        const u16* aRow = ys0 + ((size_t)t * B_ + b0 + col) * H_ + kg * 8;
#pragma unroll
        for (int i = 0; i < 32; ++i) af[i].v = *(const s16x8*)(aRow + i * 32);
#pragma unroll
        for (int i = 0; i < 32; i += 2) {
          const int kb0 = ((i * 32 + kg * 8) << 1);
          const int kb1 = (((i + 1) * 32 + kg * 8) << 1);
          acc0 = MFMA16(af[i].v, *(const s16x8*)(w1B + (kb0 ^ sw)), acc0, 0, 0, 0);
          acc1 = MFMA16(af[i + 1].v, *(const s16x8*)(w1B + (kb1 ^ sw)), acc1, 0, 0, 0);
        }
      }
      if (t > 0) {  // h1[t-1] term: flag poll -> sc0sc1 slab load (af reused)
        poll_flags(h1d + ((size_t)(t - 1) * 4 + bt) * 64, lane);
        const u16* hRow = h1rot + ((size_t)((t - 1) & 7)) * (B_ * H_) +
                          (size_t)(b0 + col) * H_ + kg * 8;
#pragma unroll
        for (int i = 0; i < 32; ++i)
          asm volatile("global_load_dwordx4 %0, %1, off offset:%c2 sc0 sc1"
                       : "=v"(af[i].v) : "v"(hRow), "n"(i * 64) : "memory");
        asm volatile("s_waitcnt vmcnt(0)" ::: "memory");
        __builtin_amdgcn_sched_barrier(0);
#pragma unroll
        for (int i = 0; i < 32; i += 2) {
          const int kb0 = 2048 + ((i * 32 + kg * 8) << 1);
          const int kb1 = 2048 + (((i + 1) * 32 + kg * 8) << 1);
          acc0 = MFMA16(af[i].v, *(const s16x8*)(w1B + (kb0 ^ sw)), acc0, 0, 0, 0);
          acc1 = MFMA16(af[i + 1].v, *(const s16x8*)(w1B + (kb1 ^ sw)), acc1, 0, 0, 0);
        }
      }
      f32x4 aH = acc0 + acc1;
      u16* hc = h1rot + ((size_t)(t & 7)) * (B_ * H_) +
                (size_t)(b0 + kg * 4) * H_ + jt;
      store_wt_u16(hc + 0 * H_, f2bf(fast_tanh(aH[0] + bias1)));
      store_wt_u16(hc + 1 * H_, f2bf(fast_tanh(aH[1] + bias1)));
      store_wt_u16(hc + 2 * H_, f2bf(fast_tanh(aH[2] + bias1)));
      store_wt_u16(hc + 3 * H_, f2bf(fast_tanh(aH[3] + bias1)));
      asm volatile("s_waitcnt vmcnt(0)" ::: "memory");
      if (lane == 0) {
        unsigned one = 1u;
        asm volatile("global_store_dword %0, %1, off sc0 sc1"
                     :: "v"(h1d + ((size_t)t * 4 + bt) * 64 + jg), "v"(one)
                     : "memory");
      }
    }
  }

  __syncthreads();  // all 8 waves done with their loops; LDS W-regions dead

  // ===================== finale: out row b = jg =====================
  const int btF = jg >> 4;  // row jg lives in b-tile btF
  if (wv == 0) poll_flags(ysd + ((size_t)(T_ - 1) * 4 + btF) * 64, lane);
  if (wv == 1) poll_flags(h1d + ((size_t)(T_ - 1) * 4 + btF) * 64, lane);
  __syncthreads();

  u16* rowbuf = (u16*)lds;  // [0,2048)=ys row bytes, [2048,4096)=h1 row bytes
  if (tid < 256) {  // ys[511] row jg: plain cached (flag-gated, write-once)
    *(s16x4*)(rowbuf + tid * 4) =
        *(const s16x4*)(ys0 + ((size_t)(T_ - 1) * B_ + jg) * H_ + tid * 4);
  } else {  // h1[511] = slot 7, row jg: sc0 sc1 (reused addresses)
    s16x4 q;
    const u16* p = h1rot + (size_t)7 * (B_ * H_) + (size_t)jg * H_ + (tid - 256) * 4;
    asm volatile("global_load_dwordx2 %0, %1, off sc0 sc1\n\ts_waitcnt vmcnt(0)"
                 : "=v"(q) : "v"(p) : "memory");
    *(s16x4*)(rowbuf + 1024 + (tid - 256) * 4) = q;
  }
  asm volatile("s_waitcnt vmcnt(0) lgkmcnt(0)" ::: "memory");
  __syncthreads();

  if (tid < OUT_) {
    const int o = tid;
    const float* wr = Wlin + (size_t)o * (2 * H_);
    float acc = blin[o];
#pragma unroll 4
    for (int k = 0; k < 2 * H_; k += 8) {
      s16x8 h = *(const s16x8*)(rowbuf + k);
      float4 w0 = *(const float4*)(wr + k);
      float4 w1 = *(const float4*)(wr + k + 4);
      acc += bf2f((u16)h[0]) * w0.x + bf2f((u16)h[1]) * w0.y +
             bf2f((u16)h[2]) * w0.z + bf2f((u16)h[3]) * w0.w +
             bf2f((u16)h[4]) * w1.x + bf2f((u16)h[5]) * w1.y +
             bf2f((u16)h[6]) * w1.z + bf2f((u16)h[7]) * w1.w;
    }
    out[jg * OUT_ + o] = 1.0f / (1.0f + expf(-acc));
  }
}

// ---------------------------------------------------------------------------
extern "C" void kernel_launch(void* const* d_in, const int* in_sizes, int n_in,
                              void* d_out, int out_size, void* d_ws, size_t ws_size,
                              hipStream_t stream) {
  const float* x    = (const float*)d_in[0];
  const float* Wih0 = (const float*)d_in[1];
  const float* Whh0 = (const float*)d_in[2];
  const float* bih0 = (const float*)d_in[3];
  const float* bhh0 = (const float*)d_in[4];
  const float* Wih1 = (const float*)d_in[5];
  const float* Whh1 = (const float*)d_in[6];
  const float* bih1 = (const float*)d_in[7];
  const float* bhh1 = (const float*)d_in[8];
  const float* Wlin = (const float*)d_in[9];
  const float* blin = (const float*)d_in[10];
  float* out = (float*)d_out;

  char* ws = (char*)d_ws;
  const size_t TBH = (size_t)T_ * B_ * H_;
  u16* xw0bf = (u16*)ws;                     // 64 MiB
  u16* ys0   = (u16*)(ws + (64ull << 20));   // 64 MiB (flag-gated, no poison)
  u16* xbf   = ys0;                          // prologue-only aliases
  u16* w0bf  = ys0 + (size_t)T_ * B_ * IN_;  //  (dead before rnn_seq writes)
  u16* h1rot = (u16*)(ws + (128ull << 20));  // 8 x 128 KiB rotation
  unsigned* ysd = (unsigned*)(ws + (129ull << 20));            // 512 KiB
  unsigned* h1d = (unsigned*)(ws + (129ull << 20) + (512u << 10));  // 512 KiB

  // zero the flag arrays (fresh every launch -> nonzero == written this run)
  hipMemsetAsync(ysd, 0, (1u << 20), stream);

  cvt_x<<<8192, 256, 0, stream>>>(x, xbf);
  cvt_w<<<256, 256, 0, stream>>>(Wih0, w0bf);
  xw0_mfma<<<dim3(16, 512), 256, 0, stream>>>(xbf, w0bf, bih0, bhh0, xw0bf);

  const int dyn_lds = 98304;  // 32K W0 + 64K W1 (proven size class)
  hipFuncSetAttribute((const void*)rnn_seq, hipFuncAttributeMaxDynamicSharedMemorySize,
                      dyn_lds);
  void* args[] = {&Whh0, &Wih1, &Whh1, &bih1, &bhh1, &Wlin, &blin,
                  &xw0bf, &ys0, &h1rot, &ysd, &h1d, &out};
  hipLaunchCooperativeKernel((const void*)rnn_seq, dim3(NBLK), dim3(NTHR), args, dyn_lds,
                             stream);
}

// Round 13
// 2296.252 us; speedup vs baseline: 3.5819x; 3.0267x over previous
//
#include <hip/hip_runtime.h>

// Problem constants: B=64, T=512, IN=256, H=1024, L=2, OUT=128
#define B_ 64
#define T_ 512
#define IN_ 256
#define H_ 1024
#define OUT_ 128
#define NBLK 64
#define NTHR 512
#define POI2 0x40004000u

typedef __attribute__((ext_vector_type(4))) float f32x4;
typedef __attribute__((ext_vector_type(8))) short s16x8;
typedef __attribute__((ext_vector_type(4))) short s16x4;
typedef unsigned short u16;

#define MFMA16 __builtin_amdgcn_mfma_f32_16x16x32_bf16

union FragU { s16x8 v; unsigned d[4]; };
union Frag4U { s16x4 v; unsigned d[2]; };

// fp32 -> bf16 RNE
__device__ __forceinline__ u16 f2bf(float f) {
  union { float f; unsigned u; } v; v.f = f;
  unsigned r = v.u + 0x7fffu + ((v.u >> 16) & 1u);
  return (u16)(r >> 16);
}
__device__ __forceinline__ float bf2f(u16 h) {
  union { unsigned u; float f; } v; v.u = ((unsigned)h) << 16;
  return v.f;
}
__device__ __forceinline__ s16x8 cvt8(const float* __restrict__ p) {
  float4 a = *(const float4*)p;
  float4 b = *(const float4*)(p + 4);
  s16x8 r;
  r[0] = (short)f2bf(a.x); r[1] = (short)f2bf(a.y);
  r[2] = (short)f2bf(a.z); r[3] = (short)f2bf(a.w);
  r[4] = (short)f2bf(b.x); r[5] = (short)f2bf(b.y);
  r[6] = (short)f2bf(b.z); r[7] = (short)f2bf(b.w);
  return r;
}

// tanh via hardware exp. Output in [-1,1] -> bf16 bit14 always 0; poison
// 0xFFFF has bit14 set. Data-poll readiness detector (R9/R11-proven).
__device__ __forceinline__ float fast_tanh(float x) {
  float e = __expf(2.0f * x);
  return 1.0f - 2.0f * __builtin_amdgcn_rcpf(e + 1.0f);
}

// Write-through 2B store to MALL (validated rounds 4-12).
__device__ __forceinline__ void store_wt_u16(u16* p, u16 v) {
  unsigned d = v;
  asm volatile("global_store_short %0, %1, off sc0 sc1" :: "v"(p), "v"(d) : "memory");
}

// ---------------------------------------------------------------------------
// prologue kernels (cvt validated rounds 3-12; xw0_mfma now stores TILED)
// TILED activation layout: buf[((t*64 + jg) << 10) + b*16 + c]  (u16)
//   -> per (t, jg-tile): contiguous 2KB [64 b][16 c]. Consumer fragment
//   af[i] (k = i*32+kg*8) = 16B at tile 2i+(kg>>1), row b0+col, c=(kg&1)*8:
//   one 64-lane load covers TWO full contiguous 512B row-spans (coalesced).
// ---------------------------------------------------------------------------
__global__ __launch_bounds__(256) void cvt_x(const float* __restrict__ x,
                                             u16* __restrict__ xbf) {
  int i4 = blockIdx.x * 256 + threadIdx.x;
  int r = i4 >> 6;
  int kc = (i4 & 63) * 4;
  int t = r >> 6, b = r & 63;
  float4 v = *(const float4*)(x + ((size_t)b * T_ + t) * IN_ + kc);
  s16x4 o;
  o[0] = (short)f2bf(v.x); o[1] = (short)f2bf(v.y);
  o[2] = (short)f2bf(v.z); o[3] = (short)f2bf(v.w);
  *(s16x4*)(xbf + (size_t)r * IN_ + kc) = o;
}

__global__ __launch_bounds__(256) void cvt_w(const float* __restrict__ w,
                                             u16* __restrict__ wbf) {
  int i = blockIdx.x * 256 + threadIdx.x;
  float4 v = *(const float4*)(w + (size_t)i * 4);
  s16x4 o;
  o[0] = (short)f2bf(v.x); o[1] = (short)f2bf(v.y);
  o[2] = (short)f2bf(v.z); o[3] = (short)f2bf(v.w);
  *(s16x4*)(wbf + (size_t)i * 4) = o;
}

__global__ __launch_bounds__(256) void xw0_mfma(const u16* __restrict__ xbf,
                                                const u16* __restrict__ w0bf,
                                                const float* __restrict__ bih,
                                                const float* __restrict__ bhh,
                                                u16* __restrict__ xw0) {
  __shared__ char ldsW[64 * 512];
  const int tid = threadIdx.x;
  const int j0 = blockIdx.x * 64;
  const int r0 = blockIdx.y * 64;

  for (int c = tid; c < 64 * 32; c += 256) {
    int r = c >> 5, kc = c & 31;
    s16x8 w = *(const s16x8*)(w0bf + (size_t)(j0 + r) * IN_ + kc * 8);
    *(s16x8*)(ldsW + r * 512 + ((kc * 16) ^ ((r & 7) << 4))) = w;
  }
  __syncthreads();

  const int wv = tid >> 6, lane = tid & 63;
  const int col = lane & 15, kg = lane >> 4;
  const int rr = r0 + wv * 16 + col;
  const u16* aRow = xbf + (size_t)rr * IN_ + kg * 8;

  f32x4 acc[4] = {};
#pragma unroll
  for (int k0 = 0; k0 < IN_; k0 += 32) {
    s16x8 a = *(const s16x8*)(aRow + k0);
#pragma unroll
    for (int n = 0; n < 4; ++n) {
      int jr = n * 16 + col;
      s16x8 b = *(const s16x8*)(ldsW + jr * 512 + ((((k0 + kg * 8) << 1)) ^ ((jr & 7) << 4)));
      acc[n] = MFMA16(a, b, acc[n], 0, 0, 0);
    }
  }
  // TILED store: t = blockIdx.y, jg-tile = blockIdx.x*4+n, b = wv*16+kg*4+q
#pragma unroll
  for (int n = 0; n < 4; ++n) {
    int j = j0 + n * 16 + col;
    float bs = bih[j] + bhh[j];
    u16* dst = xw0 + (((size_t)blockIdx.y * 64 + blockIdx.x * 4 + n) << 10) +
               (wv * 16 + kg * 4) * 16 + col;
#pragma unroll
    for (int q = 0; q < 4; ++q) dst[q * 16] = f2bf(acc[n][q] + bs);
  }
}

// ---------------------------------------------------------------------------
// Persistent cooperative kernel, R9 shape + tiled layout + P_ih split +
// pure data-poll + chunked retries. 64 blocks x 512 thr, 1 barrier/step.
// Block jg owns 16 j-cols. Waves 0-3 (b-tile bt=wv):
//   s>0: burst ys[s-1] (poll=load, chunk retries) -> dual MFMA:
//        accY (Whh0) and accP = ys[s-1]@Wih1 (-> LDS for L1 waves)
//   s<T: ys[s] = tanh(accY + xw0[s]) tiled WT store
// Waves 4-7 (bt=wv-4), t1=s-1:
//   pre-poison h1 slot (t1+4)&7; t1>0: burst h1[t1-1] -> accH (Whh1)
//   after barrier: h1[t1] = tanh(accH + P + bias) tiled WT store
// h1: depth-8 rotation; skew across blocks provably <=1 step (each L1 step
// needs ALL blocks' previous h1), so poison at +4 can never hit a reader.
// ---------------------------------------------------------------------------
__global__ __launch_bounds__(NTHR, 1) void rnn_seq(
    const float* __restrict__ Whh0, const float* __restrict__ Wih1,
    const float* __restrict__ Whh1, const float* __restrict__ bih1,
    const float* __restrict__ bhh1, const float* __restrict__ Wlin,
    const float* __restrict__ blin, const u16* __restrict__ xw0bf,
    u16* __restrict__ ys0, u16* __restrict__ h1rot, float* __restrict__ out) {
  extern __shared__ char lds[];
  char* ldsW0 = lds;                    // 16 x 2048 B (32 KB)
  char* ldsW1 = lds + 32768;            // 16 x 4096 B (64 KB)
  float* ldsP = (float*)(lds + 98304);  // [2 parity][4 bt][16 r][16 c] (8 KB)

  const int tid = threadIdx.x;
  const int jg = blockIdx.x;  // 0..63
  const int j0 = jg * 16;
  const int wv = tid >> 6, lane = tid & 63;
  const int col = lane & 15, kg = lane >> 4;
  const int sw = (col & 7) << 4;
  const int bt = wv & 3;
  const int b0 = bt * 16;
  const bool isL1 = wv >= 4;
  const int jt = j0 + col;

  // stage W0 slice (16 x 1024 bf16), swizzled
  for (int c = tid; c < 16 * 128; c += NTHR) {
    int r = c >> 7, kc = c & 127;
    s16x8 w = cvt8(Whh0 + (size_t)(j0 + r) * H_ + kc * 8);
    *(s16x8*)(ldsW0 + r * 2048 + ((kc * 16) ^ ((r & 7) << 4))) = w;
  }
  // stage W1 slice (16 x 2048 bf16): [0,1024)=Wih1, [1024,2048)=Whh1
  for (int c = tid; c < 16 * 256; c += NTHR) {
    int r = c >> 8, kc = c & 255;
    const float* src = (kc < 128) ? (Wih1 + (size_t)(j0 + r) * H_ + kc * 8)
                                  : (Whh1 + (size_t)(j0 + r) * H_ + (kc - 128) * 8);
    *(s16x8*)(ldsW1 + r * 4096 + ((kc * 16) ^ ((r & 7) << 4))) = cvt8(src);
  }
  __syncthreads();

  const float bias1 = bih1[jt] + bhh1[jt];
  // tiled burst base offsets (lane-constant parts)
  const size_t laneOff = (size_t)((kg >> 1) << 10) + (size_t)(b0 + col) * 16 + (kg & 1) * 8;

// burst + per-chunk retry: loads 32 x 16B from tiled buffer `BASE` (u16*,
// already includes laneOff), leaves fragments in af[]. One live addr reg.
#define BURST_POLL(BASE)                                                        \
  {                                                                             \
    const u16* p = (BASE);                                                      \
    _Pragma("unroll") for (int i = 0; i < 32; ++i) {                            \
      asm volatile("global_load_dwordx4 %0, %1, off sc0 sc1"                    \
                   : "=v"(af[i].v) : "v"(p) : "memory");                        \
      asm volatile("" : "+v"(p));                                               \
      p += 2048;                                                                \
    }                                                                           \
    asm volatile("s_waitcnt vmcnt(0)" ::: "memory");                            \
    __builtin_amdgcn_sched_barrier(0);                                          \
    _Pragma("unroll") for (int c = 0; c < 8; ++c) {                             \
      unsigned bad = 0u;                                                        \
      _Pragma("unroll") for (int ii = 0; ii < 4; ++ii)                          \
          bad |= af[c * 4 + ii].d[0] | af[c * 4 + ii].d[1] |                    \
                 af[c * 4 + ii].d[2] | af[c * 4 + ii].d[3];                     \
      while (__ballot((bad & POI2) != 0u) != 0ull) {                            \
        const u16* q = (BASE) + (size_t)c * 4 * 2048;                           \
        _Pragma("unroll") for (int ii = 0; ii < 4; ++ii) {                      \
          asm volatile("global_load_dwordx4 %0, %1, off sc0 sc1"                \
                       : "=v"(af[c * 4 + ii].v) : "v"(q) : "memory");           \
          asm volatile("" : "+v"(q));                                           \
          q += 2048;                                                            \
        }                                                                       \
        asm volatile("s_waitcnt vmcnt(0)" ::: "memory");                        \
        __builtin_amdgcn_sched_barrier(0);                                      \
        bad = 0u;                                                               \
        _Pragma("unroll") for (int ii = 0; ii < 4; ++ii)                        \
            bad |= af[c * 4 + ii].d[0] | af[c * 4 + ii].d[1] |                  \
                   af[c * 4 + ii].d[2] | af[c * 4 + ii].d[3];                   \
      }                                                                         \
    }                                                                           \
    __builtin_amdgcn_sched_barrier(0);                                          \
  }

  for (int s = 0; s <= T_; ++s) {
    if (!isL1) {
      // ---------------- layer-0 waves: ys[s] + P_ih[s-1] ----------------
      u16 xv0 = 0, xv1 = 0, xv2 = 0, xv3 = 0;
      if (s < T_) {  // tiled xw0 prefetch
        const u16* xq = xw0bf + (((size_t)s * 64 + jg) << 10) + (b0 + kg * 4) * 16 + col;
        xv0 = xq[0]; xv1 = xq[16]; xv2 = xq[32]; xv3 = xq[48];
      }
      f32x4 accY0 = {}, accY1 = {}, accP0 = {}, accP1 = {};
      if (s > 0) {
        FragU af[32];
        const u16* base = ys0 + (((size_t)(s - 1) * 64) << 10) + laneOff;
        BURST_POLL(base);
#pragma unroll
        for (int i = 0; i < 32; i += 2) {
          const int kb0 = ((i * 32 + kg * 8) << 1);
          const int kb1 = (((i + 1) * 32 + kg * 8) << 1);
          accY0 = MFMA16(af[i].v, *(const s16x8*)(ldsW0 + col * 2048 + (kb0 ^ sw)), accY0, 0, 0, 0);
          accP0 = MFMA16(af[i].v, *(const s16x8*)(ldsW1 + col * 4096 + (kb0 ^ sw)), accP0, 0, 0, 0);
          accY1 = MFMA16(af[i + 1].v, *(const s16x8*)(ldsW0 + col * 2048 + (kb1 ^ sw)), accY1, 0, 0, 0);
          accP1 = MFMA16(af[i + 1].v, *(const s16x8*)(ldsW1 + col * 4096 + (kb1 ^ sw)), accP1, 0, 0, 0);
        }
      }
      if (s < T_) {
        f32x4 aY = accY0 + accY1;
        u16* ysC = ys0 + (((size_t)s * 64 + jg) << 10) + (b0 + kg * 4) * 16 + col;
        store_wt_u16(ysC + 0,  f2bf(fast_tanh(aY[0] + bf2f(xv0))));
        store_wt_u16(ysC + 16, f2bf(fast_tanh(aY[1] + bf2f(xv1))));
        store_wt_u16(ysC + 32, f2bf(fast_tanh(aY[2] + bf2f(xv2))));
        store_wt_u16(ysC + 48, f2bf(fast_tanh(aY[3] + bf2f(xv3))));
      }
      if (s > 0) {  // hand P_ih[s-1] to L1 waves (parity double-buffer)
        f32x4 aP = accP0 + accP1;
        float* pT = ldsP + (s & 1) * 1024 + bt * 256 + (kg * 4) * 16 + col;
        pT[0] = aP[0]; pT[16] = aP[1]; pT[32] = aP[2]; pT[48] = aP[3];
      }
    } else {
      // ---------------- layer-1 waves: h-part (pre-barrier) ----------------
      const int t1 = s - 1;
      f32x4 accH0 = {}, accH1 = {};
      if (t1 >= 0) {  // pre-poison slot (t1+4)&7; drained by burst vmcnt(0)
        u16* pz = h1rot + (((size_t)((t1 + 4) & 7) * 64 + jg) << 10) +
                  (b0 + kg * 4) * 16 + col;
        store_wt_u16(pz + 0, 0xFFFFu);
        store_wt_u16(pz + 16, 0xFFFFu);
        store_wt_u16(pz + 32, 0xFFFFu);
        store_wt_u16(pz + 48, 0xFFFFu);
      }
      if (t1 >= 1) {
        FragU af[32];
        const u16* base = h1rot + (((size_t)((t1 - 1) & 7) * 64) << 10) + laneOff;
        BURST_POLL(base);
#pragma unroll
        for (int i = 0; i < 32; i += 2) {
          const int kb0 = 2048 + ((i * 32 + kg * 8) << 1);
          const int kb1 = 2048 + (((i + 1) * 32 + kg * 8) << 1);
          accH0 = MFMA16(af[i].v, *(const s16x8*)(ldsW1 + col * 4096 + (kb0 ^ sw)), accH0, 0, 0, 0);
          accH1 = MFMA16(af[i + 1].v, *(const s16x8*)(ldsW1 + col * 4096 + (kb1 ^ sw)), accH1, 0, 0, 0);
        }
      }
      __syncthreads();  // P_ih[t1] now in ldsP[s&1]
      if (t1 >= 0) {
        f32x4 aH = accH0 + accH1;
        const float* pT = ldsP + (s & 1) * 1024 + bt * 256 + (kg * 4) * 16 + col;
        u16* hc = h1rot + (((size_t)(t1 & 7) * 64 + jg) << 10) + (b0 + kg * 4) * 16 + col;
        store_wt_u16(hc + 0,  f2bf(fast_tanh(aH[0] + pT[0] + bias1)));
        store_wt_u16(hc + 16, f2bf(fast_tanh(aH[1] + pT[16] + bias1)));
        store_wt_u16(hc + 32, f2bf(fast_tanh(aH[2] + pT[32] + bias1)));
        store_wt_u16(hc + 48, f2bf(fast_tanh(aH[3] + pT[48] + bias1)));
      }
      continue;  // barrier already executed in this branch
    }
    __syncthreads();
  }

  __syncthreads();  // all waves done; LDS weights dead

  // ===================== finale: out row b = jg =====================
  u16* rowbuf = (u16*)lds;  // [0,1024)=ys[511] row, [1024,2048)=h1[511] row
  {
    Frag4U q;
    const int k4 = (tid & 255) * 4;
    const u16* p;
    if (tid < 256)
      p = ys0 + (((size_t)(T_ - 1) * 64 + (k4 >> 4)) << 10) + jg * 16 + (k4 & 15);
    else
      p = h1rot + (((size_t)7 * 64 + (k4 >> 4)) << 10) + jg * 16 + (k4 & 15);
    do {
      asm volatile("global_load_dwordx2 %0, %1, off sc0 sc1\n\ts_waitcnt vmcnt(0)"
                   : "=v"(q.v) : "v"(p) : "memory");
    } while (__ballot(((q.d[0] | q.d[1]) & POI2) != 0u) != 0ull);
    if (tid < 256)
      *(s16x4*)(rowbuf + k4) = q.v;
    else
      *(s16x4*)(rowbuf + 1024 + k4) = q.v;
  }
  asm volatile("s_waitcnt lgkmcnt(0)" ::: "memory");
  __syncthreads();

  if (tid < OUT_) {
    const int o = tid;
    const float* wr = Wlin + (size_t)o * (2 * H_);
    float acc = blin[o];
#pragma unroll 4
    for (int k = 0; k < 2 * H_; k += 8) {
      s16x8 h = *(const s16x8*)(rowbuf + k);
      float4 w0 = *(const float4*)(wr + k);
      float4 w1 = *(const float4*)(wr + k + 4);
      acc += bf2f((u16)h[0]) * w0.x + bf2f((u16)h[1]) * w0.y +
             bf2f((u16)h[2]) * w0.z + bf2f((u16)h[3]) * w0.w +
             bf2f((u16)h[4]) * w1.x + bf2f((u16)h[5]) * w1.y +
             bf2f((u16)h[6]) * w1.z + bf2f((u16)h[7]) * w1.w;
    }
    out[jg * OUT_ + o] = 1.0f / (1.0f + expf(-acc));
  }
}

// ---------------------------------------------------------------------------
extern "C" void kernel_launch(void* const* d_in, const int* in_sizes, int n_in,
                              void* d_out, int out_size, void* d_ws, size_t ws_size,
                              hipStream_t stream) {
  const float* x    = (const float*)d_in[0];
  const float* Wih0 = (const float*)d_in[1];
  const float* Whh0 = (const float*)d_in[2];
  const float* bih0 = (const float*)d_in[3];
  const float* bhh0 = (const float*)d_in[4];
  const float* Wih1 = (const float*)d_in[5];
  const float* Whh1 = (const float*)d_in[6];
  const float* bih1 = (const float*)d_in[7];
  const float* bhh1 = (const float*)d_in[8];
  const float* Wlin = (const float*)d_in[9];
  const float* blin = (const float*)d_in[10];
  float* out = (float*)d_out;

  char* ws = (char*)d_ws;
  const size_t TBH = (size_t)T_ * B_ * H_;
  u16* xw0bf = (u16*)ws;                     // 64 MiB (tiled)
  u16* ys0   = (u16*)(ws + (64ull << 20));   // 64 MiB (tiled, poisoned)
  u16* xbf   = ys0;                          // prologue-only aliases
  u16* w0bf  = ys0 + (size_t)T_ * B_ * IN_;  //  (dead before poisoning)
  u16* h1rot = (u16*)(ws + (128ull << 20));  // 8 x 128 KiB rotation (poisoned)

  cvt_x<<<8192, 256, 0, stream>>>(x, xbf);
  cvt_w<<<256, 256, 0, stream>>>(Wih0, w0bf);
  xw0_mfma<<<dim3(16, 512), 256, 0, stream>>>(xbf, w0bf, bih0, bhh0, xw0bf);

  // poison AFTER xw0_mfma consumed the aliased xbf/w0bf (stream-ordered)
  hipMemsetAsync(ys0, 0xFF, TBH * 2, stream);
  hipMemsetAsync(h1rot, 0xFF, (size_t)8 * B_ * H_ * 2, stream);

  const int dyn_lds = 106496;  // 32K W0 + 64K W1 + 8K P (R9-proven size)
  hipFuncSetAttribute((const void*)rnn_seq, hipFuncAttributeMaxDynamicSharedMemorySize,
                      dyn_lds);
  void* args[] = {&Whh0, &Wih1, &Whh1, &bih1, &bhh1, &Wlin,
                  &blin, &xw0bf, &ys0, &h1rot, &out};
  hipLaunchCooperativeKernel((const void*)rnn_seq, dim3(NBLK), dim3(NTHR), args, dyn_lds,
                             stream);
}

// Round 14
// 2254.804 us; speedup vs baseline: 3.6477x; 1.0184x over previous
//
#include <hip/hip_runtime.h>

// Problem constants: B=64, T=512, IN=256, H=1024, L=2, OUT=128
#define B_ 64
#define T_ 512
#define IN_ 256
#define H_ 1024
#define OUT_ 128
#define NBLK 64
#define NTHR 512
#define POI2 0x40004000u

typedef __attribute__((ext_vector_type(4))) float f32x4;
typedef __attribute__((ext_vector_type(8))) short s16x8;
typedef __attribute__((ext_vector_type(4))) short s16x4;
typedef unsigned short u16;

#define MFMA16 __builtin_amdgcn_mfma_f32_16x16x32_bf16

union FragU { s16x8 v; unsigned d[4]; };
union Frag4U { s16x4 v; unsigned d[2]; };

// fp32 -> bf16 RNE
__device__ __forceinline__ u16 f2bf(float f) {
  union { float f; unsigned u; } v; v.f = f;
  unsigned r = v.u + 0x7fffu + ((v.u >> 16) & 1u);
  return (u16)(r >> 16);
}
__device__ __forceinline__ float bf2f(u16 h) {
  union { unsigned u; float f; } v; v.u = ((unsigned)h) << 16;
  return v.f;
}
__device__ __forceinline__ s16x8 cvt8(const float* __restrict__ p) {
  float4 a = *(const float4*)p;
  float4 b = *(const float4*)(p + 4);
  s16x8 r;
  r[0] = (short)f2bf(a.x); r[1] = (short)f2bf(a.y);
  r[2] = (short)f2bf(a.z); r[3] = (short)f2bf(a.w);
  r[4] = (short)f2bf(b.x); r[5] = (short)f2bf(b.y);
  r[6] = (short)f2bf(b.z); r[7] = (short)f2bf(b.w);
  return r;
}

// tanh via hardware exp. Output in [-1,1] -> bf16 bit14 always 0; poison
// 0xFFFF has bit14 set. Data-poll readiness detector (R9/R13-proven).
__device__ __forceinline__ float fast_tanh(float x) {
  float e = __expf(2.0f * x);
  return 1.0f - 2.0f * __builtin_amdgcn_rcpf(e + 1.0f);
}

// ---------------------------------------------------------------------------
// prologue kernels (validated rounds 3-13; xw0_mfma stores TILED as in R13)
// TILED activation layout: buf[((t*64 + jg) << 10) + b*16 + c]  (u16)
// ---------------------------------------------------------------------------
__global__ __launch_bounds__(256) void cvt_x(const float* __restrict__ x,
                                             u16* __restrict__ xbf) {
  int i4 = blockIdx.x * 256 + threadIdx.x;
  int r = i4 >> 6;
  int kc = (i4 & 63) * 4;
  int t = r >> 6, b = r & 63;
  float4 v = *(const float4*)(x + ((size_t)b * T_ + t) * IN_ + kc);
  s16x4 o;
  o[0] = (short)f2bf(v.x); o[1] = (short)f2bf(v.y);
  o[2] = (short)f2bf(v.z); o[3] = (short)f2bf(v.w);
  *(s16x4*)(xbf + (size_t)r * IN_ + kc) = o;
}

__global__ __launch_bounds__(256) void cvt_w(const float* __restrict__ w,
                                             u16* __restrict__ wbf) {
  int i = blockIdx.x * 256 + threadIdx.x;
  float4 v = *(const float4*)(w + (size_t)i * 4);
  s16x4 o;
  o[0] = (short)f2bf(v.x); o[1] = (short)f2bf(v.y);
  o[2] = (short)f2bf(v.z); o[3] = (short)f2bf(v.w);
  *(s16x4*)(wbf + (size_t)i * 4) = o;
}

__global__ __launch_bounds__(256) void xw0_mfma(const u16* __restrict__ xbf,
                                                const u16* __restrict__ w0bf,
                                                const float* __restrict__ bih,
                                                const float* __restrict__ bhh,
                                                u16* __restrict__ xw0) {
  __shared__ char ldsW[64 * 512];
  const int tid = threadIdx.x;
  const int j0 = blockIdx.x * 64;
  const int r0 = blockIdx.y * 64;

  for (int c = tid; c < 64 * 32; c += 256) {
    int r = c >> 5, kc = c & 31;
    s16x8 w = *(const s16x8*)(w0bf + (size_t)(j0 + r) * IN_ + kc * 8);
    *(s16x8*)(ldsW + r * 512 + ((kc * 16) ^ ((r & 7) << 4))) = w;
  }
  __syncthreads();

  const int wv = tid >> 6, lane = tid & 63;
  const int col = lane & 15, kg = lane >> 4;
  const int rr = r0 + wv * 16 + col;
  const u16* aRow = xbf + (size_t)rr * IN_ + kg * 8;

  f32x4 acc[4] = {};
#pragma unroll
  for (int k0 = 0; k0 < IN_; k0 += 32) {
    s16x8 a = *(const s16x8*)(aRow + k0);
#pragma unroll
    for (int n = 0; n < 4; ++n) {
      int jr = n * 16 + col;
      s16x8 b = *(const s16x8*)(ldsW + jr * 512 + ((((k0 + kg * 8) << 1)) ^ ((jr & 7) << 4)));
      acc[n] = MFMA16(a, b, acc[n], 0, 0, 0);
    }
  }
#pragma unroll
  for (int n = 0; n < 4; ++n) {
    int j = j0 + n * 16 + col;
    float bs = bih[j] + bhh[j];
    u16* dst = xw0 + (((size_t)blockIdx.y * 64 + blockIdx.x * 4 + n) << 10) +
               (wv * 16 + kg * 4) * 16 + col;
#pragma unroll
    for (int q = 0; q < 4; ++q) dst[q * 16] = f2bf(acc[n][q] + bs);
  }
}

// ---------------------------------------------------------------------------
// Persistent cooperative kernel = R13 (tiled + P_ih split + data-poll +
// chunked retries) + LDS-TRANSPOSE COALESCED STORES:
// each wave stages its 16x16 bf16 output tile in a private 512B LDS tile,
// then 32 lanes emit 32 x 16B WT stores covering a contiguous 512B span
// (vs 256 x 2B scattered). 16B stores align exactly with consumer 16B
// poll-loads -> no tearing; partial visibility still carries poison bit14.
// ---------------------------------------------------------------------------
__global__ __launch_bounds__(NTHR, 1) void rnn_seq(
    const float* __restrict__ Whh0, const float* __restrict__ Wih1,
    const float* __restrict__ Whh1, const float* __restrict__ bih1,
    const float* __restrict__ bhh1, const float* __restrict__ Wlin,
    const float* __restrict__ blin, const u16* __restrict__ xw0bf,
    u16* __restrict__ ys0, u16* __restrict__ h1rot, float* __restrict__ out) {
  extern __shared__ char lds[];
  char* ldsW0 = lds;                    // 16 x 2048 B (32 KB)
  char* ldsW1 = lds + 32768;            // 16 x 4096 B (64 KB)
  float* ldsP = (float*)(lds + 98304);  // [2 parity][4 bt][16 r][16 c] (8 KB)
  char* ldsT = lds + 106496;            // 8 waves x 512 B staging (4 KB)

  const int tid = threadIdx.x;
  const int jg = blockIdx.x;  // 0..63
  const int j0 = jg * 16;
  const int wv = tid >> 6, lane = tid & 63;
  const int col = lane & 15, kg = lane >> 4;
  const int sw = (col & 7) << 4;
  const int bt = wv & 3;
  const int b0 = bt * 16;
  const bool isL1 = wv >= 4;
  const int jt = j0 + col;

  // stage W0 slice (16 x 1024 bf16), swizzled
  for (int c = tid; c < 16 * 128; c += NTHR) {
    int r = c >> 7, kc = c & 127;
    s16x8 w = cvt8(Whh0 + (size_t)(j0 + r) * H_ + kc * 8);
    *(s16x8*)(ldsW0 + r * 2048 + ((kc * 16) ^ ((r & 7) << 4))) = w;
  }
  // stage W1 slice (16 x 2048 bf16): [0,1024)=Wih1, [1024,2048)=Whh1
  for (int c = tid; c < 16 * 256; c += NTHR) {
    int r = c >> 8, kc = c & 255;
    const float* src = (kc < 128) ? (Wih1 + (size_t)(j0 + r) * H_ + kc * 8)
                                  : (Whh1 + (size_t)(j0 + r) * H_ + (kc - 128) * 8);
    *(s16x8*)(ldsW1 + r * 4096 + ((kc * 16) ^ ((r & 7) << 4))) = cvt8(src);
  }
  __syncthreads();

  const float bias1 = bih1[jt] + bhh1[jt];
  const size_t laneOff = (size_t)((kg >> 1) << 10) + (size_t)(b0 + col) * 16 + (kg & 1) * 8;
  // coalesced-store lane mapping: 32 lanes cover the wave's 512B tile
  const int stR = lane >> 1;          // 0..15 (b-row within tile), lanes < 32
  const int stC = (lane & 1) * 8;     // 0 or 8
  u16* tT = (u16*)(ldsT + wv * 512);  // private 16x16 u16 staging tile

// burst + per-chunk retry (R13-proven): 32 x 16B from tiled buffer.
#define BURST_POLL(BASE)                                                        \
  {                                                                             \
    const u16* p = (BASE);                                                      \
    _Pragma("unroll") for (int i = 0; i < 32; ++i) {                            \
      asm volatile("global_load_dwordx4 %0, %1, off sc0 sc1"                    \
                   : "=v"(af[i].v) : "v"(p) : "memory");                        \
      asm volatile("" : "+v"(p));                                               \
      p += 2048;                                                                \
    }                                                                           \
    asm volatile("s_waitcnt vmcnt(0)" ::: "memory");                            \
    __builtin_amdgcn_sched_barrier(0);                                          \
    _Pragma("unroll") for (int c = 0; c < 8; ++c) {                             \
      unsigned bad = 0u;                                                        \
      _Pragma("unroll") for (int ii = 0; ii < 4; ++ii)                          \
          bad |= af[c * 4 + ii].d[0] | af[c * 4 + ii].d[1] |                    \
                 af[c * 4 + ii].d[2] | af[c * 4 + ii].d[3];                     \
      while (__ballot((bad & POI2) != 0u) != 0ull) {                            \
        const u16* q = (BASE) + (size_t)c * 4 * 2048;                           \
        _Pragma("unroll") for (int ii = 0; ii < 4; ++ii) {                      \
          asm volatile("global_load_dwordx4 %0, %1, off sc0 sc1"                \
                       : "=v"(af[c * 4 + ii].v) : "v"(q) : "memory");           \
          asm volatile("" : "+v"(q));                                           \
          q += 2048;                                                            \
        }                                                                       \
        asm volatile("s_waitcnt vmcnt(0)" ::: "memory");                        \
        __builtin_amdgcn_sched_barrier(0);                                      \
        bad = 0u;                                                               \
        _Pragma("unroll") for (int ii = 0; ii < 4; ++ii)                        \
            bad |= af[c * 4 + ii].d[0] | af[c * 4 + ii].d[1] |                  \
                   af[c * 4 + ii].d[2] | af[c * 4 + ii].d[3];                   \
      }                                                                         \
    }                                                                           \
    __builtin_amdgcn_sched_barrier(0);                                          \
  }

// transpose-in-LDS then 32 x 16B coalesced WT stores of the wave's tile.
// V0..V3 are the 4 bf16 outputs (rows kg*4..kg*4+3, col). DSTBASE = u16*
// tile base (b=0,c=0).
#define STORE_TILE16(DSTBASE, V0, V1, V2, V3)                                   \
  {                                                                             \
    tT[(kg * 4 + 0) * 16 + col] = (V0);                                         \
    tT[(kg * 4 + 1) * 16 + col] = (V1);                                         \
    tT[(kg * 4 + 2) * 16 + col] = (V2);                                         \
    tT[(kg * 4 + 3) * 16 + col] = (V3);                                         \
    asm volatile("s_waitcnt lgkmcnt(0)" ::: "memory");                          \
    __builtin_amdgcn_sched_barrier(0);                                          \
    if (lane < 32) {                                                            \
      s16x8 vv = *(const s16x8*)(tT + stR * 16 + stC);                          \
      u16* dp = (DSTBASE) + stR * 16 + stC;                                     \
      asm volatile("global_store_dwordx4 %0, %1, off sc0 sc1"                   \
                   :: "v"(dp), "v"(vv) : "memory");                             \
    }                                                                           \
  }

  for (int s = 0; s <= T_; ++s) {
    if (!isL1) {
      // ---------------- layer-0 waves: ys[s] + P_ih[s-1] ----------------
      u16 xv0 = 0, xv1 = 0, xv2 = 0, xv3 = 0;
      if (s < T_) {
        const u16* xq = xw0bf + (((size_t)s * 64 + jg) << 10) + (b0 + kg * 4) * 16 + col;
        xv0 = xq[0]; xv1 = xq[16]; xv2 = xq[32]; xv3 = xq[48];
      }
      f32x4 accY0 = {}, accY1 = {}, accP0 = {}, accP1 = {};
      if (s > 0) {
        FragU af[32];
        const u16* base = ys0 + (((size_t)(s - 1) * 64) << 10) + laneOff;
        BURST_POLL(base);
#pragma unroll
        for (int i = 0; i < 32; i += 2) {
          const int kb0 = ((i * 32 + kg * 8) << 1);
          const int kb1 = (((i + 1) * 32 + kg * 8) << 1);
          accY0 = MFMA16(af[i].v, *(const s16x8*)(ldsW0 + col * 2048 + (kb0 ^ sw)), accY0, 0, 0, 0);
          accP0 = MFMA16(af[i].v, *(const s16x8*)(ldsW1 + col * 4096 + (kb0 ^ sw)), accP0, 0, 0, 0);
          accY1 = MFMA16(af[i + 1].v, *(const s16x8*)(ldsW0 + col * 2048 + (kb1 ^ sw)), accY1, 0, 0, 0);
          accP1 = MFMA16(af[i + 1].v, *(const s16x8*)(ldsW1 + col * 4096 + (kb1 ^ sw)), accP1, 0, 0, 0);
        }
      }
      if (s < T_) {
        f32x4 aY = accY0 + accY1;
        u16* dbase = ys0 + (((size_t)s * 64 + jg) << 10) + b0 * 16;
        STORE_TILE16(dbase, f2bf(fast_tanh(aY[0] + bf2f(xv0))),
                     f2bf(fast_tanh(aY[1] + bf2f(xv1))),
                     f2bf(fast_tanh(aY[2] + bf2f(xv2))),
                     f2bf(fast_tanh(aY[3] + bf2f(xv3))));
      }
      if (s > 0) {  // hand P_ih[s-1] to L1 waves (parity double-buffer)
        f32x4 aP = accP0 + accP1;
        float* pT = ldsP + (s & 1) * 1024 + bt * 256 + (kg * 4) * 16 + col;
        pT[0] = aP[0]; pT[16] = aP[1]; pT[32] = aP[2]; pT[48] = aP[3];
      }
    } else {
      // ---------------- layer-1 waves: h-part (pre-barrier) ----------------
      const int t1 = s - 1;
      f32x4 accH0 = {}, accH1 = {};
      if (t1 >= 0 && lane < 32) {  // pre-poison slot (t1+4)&7, 16B coalesced
        u16* pz = h1rot + (((size_t)((t1 + 4) & 7) * 64 + jg) << 10) +
                  b0 * 16 + stR * 16 + stC;
        FragU pf;
        pf.d[0] = pf.d[1] = pf.d[2] = pf.d[3] = 0xFFFFFFFFu;
        asm volatile("global_store_dwordx4 %0, %1, off sc0 sc1"
                     :: "v"(pz), "v"(pf.v) : "memory");
      }
      if (t1 >= 1) {
        FragU af[32];
        const u16* base = h1rot + (((size_t)((t1 - 1) & 7) * 64) << 10) + laneOff;
        BURST_POLL(base);  // vmcnt(0) inside also drains the poison stores
#pragma unroll
        for (int i = 0; i < 32; i += 2) {
          const int kb0 = 2048 + ((i * 32 + kg * 8) << 1);
          const int kb1 = 2048 + (((i + 1) * 32 + kg * 8) << 1);
          accH0 = MFMA16(af[i].v, *(const s16x8*)(ldsW1 + col * 4096 + (kb0 ^ sw)), accH0, 0, 0, 0);
          accH1 = MFMA16(af[i + 1].v, *(const s16x8*)(ldsW1 + col * 4096 + (kb1 ^ sw)), accH1, 0, 0, 0);
        }
      } else {
        // still must drain the poison stores before this step's data stores
        asm volatile("s_waitcnt vmcnt(0)" ::: "memory");
      }
      __syncthreads();  // P_ih[t1] now in ldsP[s&1]
      if (t1 >= 0) {
        f32x4 aH = accH0 + accH1;
        const float* pT = ldsP + (s & 1) * 1024 + bt * 256 + (kg * 4) * 16 + col;
        u16* dbase = h1rot + (((size_t)(t1 & 7) * 64 + jg) << 10) + b0 * 16;
        STORE_TILE16(dbase, f2bf(fast_tanh(aH[0] + pT[0] + bias1)),
                     f2bf(fast_tanh(aH[1] + pT[16] + bias1)),
                     f2bf(fast_tanh(aH[2] + pT[32] + bias1)),
                     f2bf(fast_tanh(aH[3] + pT[48] + bias1)));
      }
      continue;  // barrier already executed in this branch
    }
    __syncthreads();
  }

  __syncthreads();  // all waves done; LDS weights dead

  // ===================== finale: out row b = jg =====================
  u16* rowbuf = (u16*)lds;  // [0,1024)=ys[511] row, [1024,2048)=h1[511] row
  {
    Frag4U q;
    const int k4 = (tid & 255) * 4;
    const u16* p;
    if (tid < 256)
      p = ys0 + (((size_t)(T_ - 1) * 64 + (k4 >> 4)) << 10) + jg * 16 + (k4 & 15);
    else
      p = h1rot + (((size_t)7 * 64 + (k4 >> 4)) << 10) + jg * 16 + (k4 & 15);
    do {
      asm volatile("global_load_dwordx2 %0, %1, off sc0 sc1\n\ts_waitcnt vmcnt(0)"
                   : "=v"(q.v) : "v"(p) : "memory");
    } while (__ballot(((q.d[0] | q.d[1]) & POI2) != 0u) != 0ull);
    if (tid < 256)
      *(s16x4*)(rowbuf + k4) = q.v;
    else
      *(s16x4*)(rowbuf + 1024 + k4) = q.v;
  }
  asm volatile("s_waitcnt lgkmcnt(0)" ::: "memory");
  __syncthreads();

  if (tid < OUT_) {
    const int o = tid;
    const float* wr = Wlin + (size_t)o * (2 * H_);
    float acc = blin[o];
#pragma unroll 4
    for (int k = 0; k < 2 * H_; k += 8) {
      s16x8 h = *(const s16x8*)(rowbuf + k);
      float4 w0 = *(const float4*)(wr + k);
      float4 w1 = *(const float4*)(wr + k + 4);
      acc += bf2f((u16)h[0]) * w0.x + bf2f((u16)h[1]) * w0.y +
             bf2f((u16)h[2]) * w0.z + bf2f((u16)h[3]) * w0.w +
             bf2f((u16)h[4]) * w1.x + bf2f((u16)h[5]) * w1.y +
             bf2f((u16)h[6]) * w1.z + bf2f((u16)h[7]) * w1.w;
    }
    out[jg * OUT_ + o] = 1.0f / (1.0f + expf(-acc));
  }
}

// ---------------------------------------------------------------------------
extern "C" void kernel_launch(void* const* d_in, const int* in_sizes, int n_in,
                              void* d_out, int out_size, void* d_ws, size_t ws_size,
                              hipStream_t stream) {
  const float* x    = (const float*)d_in[0];
  const float* Wih0 = (const float*)d_in[1];
  const float* Whh0 = (const float*)d_in[2];
  const float* bih0 = (const float*)d_in[3];
  const float* bhh0 = (const float*)d_in[4];
  const float* Wih1 = (const float*)d_in[5];
  const float* Whh1 = (const float*)d_in[6];
  const float* bih1 = (const float*)d_in[7];
  const float* bhh1 = (const float*)d_in[8];
  const float* Wlin = (const float*)d_in[9];
  const float* blin = (const float*)d_in[10];
  float* out = (float*)d_out;

  char* ws = (char*)d_ws;
  const size_t TBH = (size_t)T_ * B_ * H_;
  u16* xw0bf = (u16*)ws;                     // 64 MiB (tiled)
  u16* ys0   = (u16*)(ws + (64ull << 20));   // 64 MiB (tiled, poisoned)
  u16* xbf   = ys0;                          // prologue-only aliases
  u16* w0bf  = ys0 + (size_t)T_ * B_ * IN_;  //  (dead before poisoning)
  u16* h1rot = (u16*)(ws + (128ull << 20));  // 8 x 128 KiB rotation (poisoned)

  cvt_x<<<8192, 256, 0, stream>>>(x, xbf);
  cvt_w<<<256, 256, 0, stream>>>(Wih0, w0bf);
  xw0_mfma<<<dim3(16, 512), 256, 0, stream>>>(xbf, w0bf, bih0, bhh0, xw0bf);

  // poison AFTER xw0_mfma consumed the aliased xbf/w0bf (stream-ordered)
  hipMemsetAsync(ys0, 0xFF, TBH * 2, stream);
  hipMemsetAsync(h1rot, 0xFF, (size_t)8 * B_ * H_ * 2, stream);

  const int dyn_lds = 110592;  // 32K W0 + 64K W1 + 8K P + 4K transpose tiles
  hipFuncSetAttribute((const void*)rnn_seq, hipFuncAttributeMaxDynamicSharedMemorySize,
                      dyn_lds);
  void* args[] = {&Whh0, &Wih1, &Whh1, &bih1, &bhh1, &Wlin,
                  &blin, &xw0bf, &ys0, &h1rot, &out};
  hipLaunchCooperativeKernel((const void*)rnn_seq, dim3(NBLK), dim3(NTHR), args, dyn_lds,
                             stream);
}